// Round 2
// baseline (545.986 us; speedup 1.0000x reference)
//
#include <hip/hip_runtime.h>

#define T_LEN 120000
#define LBLK 200          // samples per scan block
#define PBLK 600          // number of scan blocks (LBLK*PBLK == T_LEN)
#define CCH 8             // matmul chunk length in t
#define NCHUNK (LBLK / CCH)
#define BATCH 4
#define K0 200            // first valid block (t = 40000)
#define NKV 200           // valid blocks (t in [40000, 80000))
#define NVALID 10240000.0 // 4 * 64 * 40000

__device__ __forceinline__ float fast_tanh(float x) {
  float e = __expf(2.0f * x);
  return 1.0f - 2.0f / (e + 1.0f);
}

// Canonicalize coefficients to double regardless of how the harness stored
// the reference's float64 arrays (f64 kept, or downcast to f32).
// Detection: true a2[0] = r^2 in (0.9, 1.0). If the buffer is f32, the
// double-reinterpretation of the first 8 bytes has a wildly different
// exponent, so the window test fails. Branch is data-stable -> graph-safe.
// Neither branch reads past the f32 footprint unless the buffer is f64.
__global__ __launch_bounds__(64) void canon_coeffs(
    const void* a1p, const void* a2p, const void* b0p,
    double* ca1, double* ca2, double* cb0, double* wsum)
{
  __shared__ int isf64;
  if (threadIdx.x == 0) {
    double probe = *(const double*)a2p;
    isf64 = (probe > 0.9 && probe < 1.0) ? 1 : 0;
    *wsum = 0.0;
  }
  __syncthreads();
  int ch = threadIdx.x;
  if (isf64) {
    ca1[ch] = ((const double*)a1p)[ch];
    ca2[ch] = ((const double*)a2p)[ch];
    cb0[ch] = ((const double*)b0p)[ch];
  } else {
    ca1[ch] = (double)((const float*)a1p)[ch];
    ca2[ch] = (double)((const float*)a2p)[ch];
    cb0[ch] = (double)((const float*)b0p)[ch];
  }
}

// Pass 1: per (row, block) forced response with zero initial state.
// rows r: r = i*8 + d*4 + b  (i: 0=pred 1=target, d: 0=fwd 1=bwd, b: batch)
__global__ __launch_bounds__(64) void pass1(
    const float* __restrict__ pred, const float* __restrict__ tgt,
    const double* __restrict__ a1, const double* __restrict__ a2,
    const double* __restrict__ b0, double* __restrict__ fbuf)
{
  int k = blockIdx.x, r = blockIdx.y;
  int i = r >> 3, d = (r >> 2) & 1, b = r & 3;
  const float* sig = (i ? tgt : pred) + b * T_LEN;
  __shared__ float xs[LBLK];
  int base = k * LBLK;
  for (int j = threadIdx.x; j < LBLK; j += 64)
    xs[j] = d ? sig[T_LEN - 1 - (base + j)] : sig[base + j];
  __syncthreads();
  int ch = threadIdx.x;
  double A1 = a1[ch], A2 = a2[ch], B0 = b0[ch];
  double y1 = 0.0, y2 = 0.0;
  for (int j = 0; j < LBLK; ++j) {
    double y = fma(-A1, y1, fma(-A2, y2, B0 * (double)xs[j]));
    y2 = y1; y1 = y;
  }
  int s = r * 64 + ch;
  ((double2*)fbuf)[k * 1024 + s] = make_double2(y1, y2);
}

// Pass 2: serial block-scan over P blocks: v <- A^L v + f_k; store v per block.
__global__ __launch_bounds__(256) void pass2(
    const double* __restrict__ a1, const double* __restrict__ a2,
    const double* __restrict__ fbuf, double* __restrict__ ibuf)
{
  int s = blockIdx.x * 256 + threadIdx.x; // scan id 0..1023
  int ch = s & 63;
  double A1 = a1[ch], A2 = a2[ch];
  // A^L by repeated squaring; A = [[-a1,-a2],[1,0]]
  double m00 = -A1, m01 = -A2, m10 = 1.0, m11 = 0.0;
  double r00 = 1.0, r01 = 0.0, r10 = 0.0, r11 = 1.0;
  int e = LBLK;
  while (e) {
    if (e & 1) {
      double t00 = r00 * m00 + r01 * m10, t01 = r00 * m01 + r01 * m11;
      double t10 = r10 * m00 + r11 * m10, t11 = r10 * m01 + r11 * m11;
      r00 = t00; r01 = t01; r10 = t10; r11 = t11;
    }
    e >>= 1;
    if (e) {
      double t00 = m00 * m00 + m01 * m10, t01 = m00 * m01 + m01 * m11;
      double t10 = m10 * m00 + m11 * m10, t11 = m10 * m01 + m11 * m11;
      m00 = t00; m01 = t01; m10 = t10; m11 = t11;
    }
  }
  double y1 = 0.0, y2 = 0.0;
  #pragma unroll 8
  for (int k = 0; k < PBLK; ++k) {
    ((double2*)ibuf)[k * 1024 + s] = make_double2(y1, y2);
    double2 f = ((const double2*)fbuf)[k * 1024 + s];
    double n1 = r00 * y1 + r01 * y2 + f.x;
    double n2 = r10 * y1 + r11 * y2 + f.y;
    y1 = n1; y2 = n2;
  }
  ((double2*)ibuf)[PBLK * 1024 + s] = make_double2(y1, y2);
}

// Pass 3: per (valid block k, batch b): reconstruct exact states for all
// 2 inputs x (64 fwd + 64 bwd) channels, fused matvec+tanh+|diff| reduce.
// Backward channels run the INVERSE recurrence from the block-end state so
// they emit y in ascending t (poles at 1/r => growth e^{L(1-r)} ~ 1.02, safe).
__global__ __launch_bounds__(256) void pass3(
    const float* __restrict__ pred, const float* __restrict__ tgt,
    const double* __restrict__ a1, const double* __restrict__ a2,
    const double* __restrict__ b0, const float* __restrict__ W,
    const double* __restrict__ ibuf, double* __restrict__ wsum)
{
  int k = K0 + blockIdx.x;
  int b = blockIdx.y;
  int tid = threadIdx.x;
  __shared__ float xs[2][LBLK];
  __shared__ float ytile[2][CCH][128];
  __shared__ float red[4];

  // stage x for this block (same t-range serves fwd and bwd channels)
  for (int idx = tid; idx < 2 * LBLK; idx += 256) {
    int ii = idx / LBLK, j = idx - ii * LBLK;
    const float* sig = (ii ? tgt : pred) + b * T_LEN;
    xs[ii][j] = sig[k * LBLK + j];
  }

  // W row for this thread's output o, kept in registers (128 VGPRs)
  int o = tid & 63;
  float4 w4[32];
  const float4* Wp = (const float4*)(W + o * 128);
  #pragma unroll
  for (int c4 = 0; c4 < 32; ++c4) w4[c4] = Wp[c4];

  int g = tid >> 6;           // wave id: g = i*2 + d
  int i = g >> 1, d = g & 1, ch = tid & 63;
  int s = (i * 8 + d * 4 + b) * 64 + ch;
  double A1 = a1[ch], A2 = a2[ch], B0 = b0[ch];
  double invA2 = 1.0 / A2;
  double st0, st1;
  if (d == 0) {
    double2 v = ((const double2*)ibuf)[k * 1024 + s];   // (y[kL-1], y[kL-2])
    st0 = v.x; st1 = v.y;
  } else {
    // end state of bwd scan block k' = P-1-k is ibuf[P-k]: (y[u_e], y[u_e-1])
    double2 v = ((const double2*)ibuf)[(PBLK - k) * 1024 + s];
    st0 = v.x; st1 = v.y;
  }
  __syncthreads();

  float loss = 0.0f;
  for (int cc = 0; cc < NCHUNK; ++cc) {
    // ---- recurrence phase (wave-uniform direction, no divergence) ----
    if (d == 0) {
      #pragma unroll
      for (int j = 0; j < CCH; ++j) {
        double x = (double)xs[i][cc * CCH + j];
        double y = fma(-A1, st0, fma(-A2, st1, B0 * x));
        ytile[i][j][ch] = (float)y;
        st1 = st0; st0 = y;
      }
    } else {
      #pragma unroll
      for (int j = 0; j < CCH; ++j) {
        double x = (double)xs[i][cc * CCH + j];  // x_orig[t] == x_sig[u]
        ytile[i][j][64 + ch] = (float)st0;       // y[u] belongs at t
        double ym2 = (fma(-A1, st1, B0 * x) - st0) * invA2;
        st0 = st1; st1 = ym2;
      }
    }
    __syncthreads();
    // ---- matmul phase: thread computes output o for j in {g, g+4}, both inputs
    float zp0 = 0.f, zt0 = 0.f, zp1 = 0.f, zt1 = 0.f;
    const float4* p0 = (const float4*)&ytile[0][g][0];
    const float4* t0 = (const float4*)&ytile[1][g][0];
    const float4* p1 = (const float4*)&ytile[0][g + 4][0];
    const float4* t1 = (const float4*)&ytile[1][g + 4][0];
    #pragma unroll 8
    for (int c4 = 0; c4 < 32; ++c4) {
      float4 w = w4[c4];
      float4 va = p0[c4], vb = t0[c4], vc = p1[c4], vd = t1[c4];
      zp0 = fmaf(w.x, va.x, zp0); zp0 = fmaf(w.y, va.y, zp0);
      zp0 = fmaf(w.z, va.z, zp0); zp0 = fmaf(w.w, va.w, zp0);
      zt0 = fmaf(w.x, vb.x, zt0); zt0 = fmaf(w.y, vb.y, zt0);
      zt0 = fmaf(w.z, vb.z, zt0); zt0 = fmaf(w.w, vb.w, zt0);
      zp1 = fmaf(w.x, vc.x, zp1); zp1 = fmaf(w.y, vc.y, zp1);
      zp1 = fmaf(w.z, vc.z, zp1); zp1 = fmaf(w.w, vc.w, zp1);
      zt1 = fmaf(w.x, vd.x, zt1); zt1 = fmaf(w.y, vd.y, zt1);
      zt1 = fmaf(w.z, vd.z, zt1); zt1 = fmaf(w.w, vd.w, zt1);
    }
    loss += fabsf(fast_tanh(zp0) - fast_tanh(zt0));
    loss += fabsf(fast_tanh(zp1) - fast_tanh(zt1));
    __syncthreads();
  }

  // block reduction -> one double atomic per workgroup
  #pragma unroll
  for (int off = 32; off > 0; off >>= 1) loss += __shfl_down(loss, off);
  if ((tid & 63) == 0) red[tid >> 6] = loss;
  __syncthreads();
  if (tid == 0) atomicAdd(wsum, (double)(red[0] + red[1] + red[2] + red[3]));
}

__global__ void finalize(const double* __restrict__ wsum, float* __restrict__ out) {
  out[0] = (float)(wsum[0] / NVALID);
}

extern "C" void kernel_launch(void* const* d_in, const int* in_sizes, int n_in,
                              void* d_out, int out_size, void* d_ws, size_t ws_size,
                              hipStream_t stream) {
  const float* pred = (const float*)d_in[0];
  const float* tgt  = (const float*)d_in[1];
  const float* W    = (const float*)d_in[5];
  float* out = (float*)d_out;

  double* base = (double*)d_ws;
  double* wsum = base;                      // [1] (pad to 8)
  double* ca1  = base + 8;                  // [64]
  double* ca2  = base + 72;                 // [64]
  double* cb0  = base + 136;                // [64]
  double* fbuf = base + 200;                // [P][1024][2]
  double* ibuf = fbuf + (size_t)PBLK * 1024 * 2;  // [P+1][1024][2]

  canon_coeffs<<<1, 64, 0, stream>>>(d_in[2], d_in[3], d_in[4], ca1, ca2, cb0, wsum);
  pass1<<<dim3(PBLK, 16), 64, 0, stream>>>(pred, tgt, ca1, ca2, cb0, fbuf);
  pass2<<<dim3(4), 256, 0, stream>>>(ca1, ca2, fbuf, ibuf);
  pass3<<<dim3(NKV, BATCH), 256, 0, stream>>>(pred, tgt, ca1, ca2, cb0, W, ibuf, wsum);
  finalize<<<1, 1, 0, stream>>>(wsum, out);
}

// Round 3
// 287.812 us; speedup vs baseline: 1.8970x; 1.8970x over previous
//
#include <hip/hip_runtime.h>

#define T_LEN 120000
#define LBLK 200          // samples per scan block
#define PBLK 600          // number of scan blocks (LBLK*PBLK == T_LEN)
#define CCH 8             // matmul chunk length in t
#define NCHUNK (LBLK / CCH)
#define BATCH 4
#define K0 200            // first valid block (t = 40000)
#define NKV 200           // valid blocks (t in [40000, 80000))
#define NVALID 10240000.0 // 4 * 64 * 40000

__device__ __forceinline__ float fast_tanh(float x) {
  float e = __expf(2.0f * x);
  return 1.0f - 2.0f / (e + 1.0f);
}

// Canonicalize coefficients to double regardless of how the harness stored
// the reference's float64 arrays (f64 kept, or downcast to f32).
__global__ __launch_bounds__(64) void canon_coeffs(
    const void* a1p, const void* a2p, const void* b0p,
    double* ca1, double* ca2, double* cb0, double* wsum)
{
  __shared__ int isf64;
  if (threadIdx.x == 0) {
    double probe = *(const double*)a2p;
    isf64 = (probe > 0.9 && probe < 1.0) ? 1 : 0;
    *wsum = 0.0;
  }
  __syncthreads();
  int ch = threadIdx.x;
  if (isf64) {
    ca1[ch] = ((const double*)a1p)[ch];
    ca2[ch] = ((const double*)a2p)[ch];
    cb0[ch] = ((const double*)b0p)[ch];
  } else {
    ca1[ch] = (double)((const float*)a1p)[ch];
    ca2[ch] = (double)((const float*)a2p)[ch];
    cb0[ch] = (double)((const float*)b0p)[ch];
  }
}

// Pass 1: per (row, block) forced response with zero initial state.
// rows r: r = i*8 + d*4 + b  (i: 0=pred 1=target, d: 0=fwd 1=bwd, b: batch)
__global__ __launch_bounds__(64) void pass1(
    const float* __restrict__ pred, const float* __restrict__ tgt,
    const double* __restrict__ a1, const double* __restrict__ a2,
    const double* __restrict__ b0, double* __restrict__ fbuf)
{
  int k = blockIdx.x, r = blockIdx.y;
  int i = r >> 3, d = (r >> 2) & 1, b = r & 3;
  const float* sig = (i ? tgt : pred) + b * T_LEN;
  __shared__ float xs[LBLK];
  int base = k * LBLK;
  for (int j = threadIdx.x; j < LBLK; j += 64)
    xs[j] = d ? sig[T_LEN - 1 - (base + j)] : sig[base + j];
  __syncthreads();
  int ch = threadIdx.x;
  double A1 = a1[ch], A2 = a2[ch], B0 = b0[ch];
  double y1 = 0.0, y2 = 0.0;
  for (int j = 0; j < LBLK; ++j) {
    double y = fma(-A1, y1, fma(-A2, y2, B0 * (double)xs[j]));
    y2 = y1; y1 = y;
  }
  int s = r * 64 + ch;
  ((double2*)fbuf)[k * 1024 + s] = make_double2(y1, y2);
}

// Pass 2: serial block-scan over P blocks: v <- A^L v + f_k; store v per block.
__global__ __launch_bounds__(256) void pass2(
    const double* __restrict__ a1, const double* __restrict__ a2,
    const double* __restrict__ fbuf, double* __restrict__ ibuf)
{
  int s = blockIdx.x * 256 + threadIdx.x; // scan id 0..1023
  int ch = s & 63;
  double A1 = a1[ch], A2 = a2[ch];
  // A^L by repeated squaring; A = [[-a1,-a2],[1,0]]
  double m00 = -A1, m01 = -A2, m10 = 1.0, m11 = 0.0;
  double r00 = 1.0, r01 = 0.0, r10 = 0.0, r11 = 1.0;
  int e = LBLK;
  while (e) {
    if (e & 1) {
      double t00 = r00 * m00 + r01 * m10, t01 = r00 * m01 + r01 * m11;
      double t10 = r10 * m00 + r11 * m10, t11 = r10 * m01 + r11 * m11;
      r00 = t00; r01 = t01; r10 = t10; r11 = t11;
    }
    e >>= 1;
    if (e) {
      double t00 = m00 * m00 + m01 * m10, t01 = m00 * m01 + m01 * m11;
      double t10 = m10 * m00 + m11 * m10, t11 = m10 * m01 + m11 * m11;
      m00 = t00; m01 = t01; m10 = t10; m11 = t11;
    }
  }
  double y1 = 0.0, y2 = 0.0;
  #pragma unroll 8
  for (int k = 0; k < PBLK; ++k) {
    ((double2*)ibuf)[k * 1024 + s] = make_double2(y1, y2);
    double2 f = ((const double2*)fbuf)[k * 1024 + s];
    double n1 = r00 * y1 + r01 * y2 + f.x;
    double n2 = r10 * y1 + r11 * y2 + f.y;
    y1 = n1; y2 = n2;
  }
  ((double2*)ibuf)[PBLK * 1024 + s] = make_double2(y1, y2);
}

// Pass 3: per (valid block k, batch b): reconstruct exact states for all
// 2 inputs x (64 fwd + 64 bwd) channels, fused matvec+tanh+|diff| reduce.
__global__ __launch_bounds__(256) void pass3(
    const float* __restrict__ pred, const float* __restrict__ tgt,
    const double* __restrict__ a1, const double* __restrict__ a2,
    const double* __restrict__ b0, const float* __restrict__ W,
    const double* __restrict__ ibuf, double* __restrict__ wsum)
{
  int k = K0 + blockIdx.x;
  int b = blockIdx.y;
  int tid = threadIdx.x;
  __shared__ float xs[2][LBLK];
  __shared__ float ytile[2][CCH][128];
  __shared__ float red[4];

  // stage x for this block (same t-range serves fwd and bwd channels)
  for (int idx = tid; idx < 2 * LBLK; idx += 256) {
    int ii = idx / LBLK, j = idx - ii * LBLK;
    const float* sig = (ii ? tgt : pred) + b * T_LEN;
    xs[ii][j] = sig[k * LBLK + j];
  }

  // W row for this thread's output o, kept in registers (128 VGPRs).
  // FULL unroll everywhere w4 is indexed -> constant indices -> SROA keeps
  // it in VGPRs (round-2 bug: partial unroll demoted it to scratch).
  int o = tid & 63;
  float4 w4[32];
  const float4* Wp = (const float4*)(W + o * 128);
  #pragma unroll
  for (int c4 = 0; c4 < 32; ++c4) w4[c4] = Wp[c4];

  int g = tid >> 6;           // wave id: g = i*2 + d
  int i = g >> 1, d = g & 1, ch = tid & 63;
  int s = (i * 8 + d * 4 + b) * 64 + ch;
  double A1 = a1[ch], A2 = a2[ch], B0 = b0[ch];
  double invA2 = 1.0 / A2;
  double st0, st1;
  if (d == 0) {
    double2 v = ((const double2*)ibuf)[k * 1024 + s];   // (y[kL-1], y[kL-2])
    st0 = v.x; st1 = v.y;
  } else {
    // end state of bwd scan block k' = P-1-k is ibuf[P-k]: (y[u_e], y[u_e-1])
    double2 v = ((const double2*)ibuf)[(PBLK - k) * 1024 + s];
    st0 = v.x; st1 = v.y;
  }
  __syncthreads();

  float loss = 0.0f;
  for (int cc = 0; cc < NCHUNK; ++cc) {
    // ---- recurrence phase (wave-uniform direction, no divergence) ----
    if (d == 0) {
      #pragma unroll
      for (int j = 0; j < CCH; ++j) {
        double x = (double)xs[i][cc * CCH + j];
        double y = fma(-A1, st0, fma(-A2, st1, B0 * x));
        ytile[i][j][ch] = (float)y;
        st1 = st0; st0 = y;
      }
    } else {
      #pragma unroll
      for (int j = 0; j < CCH; ++j) {
        double x = (double)xs[i][cc * CCH + j];  // x_orig[t] == x_sig[u]
        ytile[i][j][64 + ch] = (float)st0;       // y[u] belongs at t
        double ym2 = (fma(-A1, st1, B0 * x) - st0) * invA2;
        st0 = st1; st1 = ym2;
      }
    }
    __syncthreads();
    // ---- matmul phase: thread computes output o for j in {g, g+4}, both inputs
    float zp0 = 0.f, zt0 = 0.f, zp1 = 0.f, zt1 = 0.f;
    const float4* p0 = (const float4*)&ytile[0][g][0];
    const float4* t0 = (const float4*)&ytile[1][g][0];
    const float4* p1 = (const float4*)&ytile[0][g + 4][0];
    const float4* t1 = (const float4*)&ytile[1][g + 4][0];
    #pragma unroll
    for (int c4 = 0; c4 < 32; ++c4) {
      float4 w = w4[c4];
      float4 va = p0[c4], vb = t0[c4], vc = p1[c4], vd = t1[c4];
      zp0 = fmaf(w.x, va.x, zp0); zp0 = fmaf(w.y, va.y, zp0);
      zp0 = fmaf(w.z, va.z, zp0); zp0 = fmaf(w.w, va.w, zp0);
      zt0 = fmaf(w.x, vb.x, zt0); zt0 = fmaf(w.y, vb.y, zt0);
      zt0 = fmaf(w.z, vb.z, zt0); zt0 = fmaf(w.w, vb.w, zt0);
      zp1 = fmaf(w.x, vc.x, zp1); zp1 = fmaf(w.y, vc.y, zp1);
      zp1 = fmaf(w.z, vc.z, zp1); zp1 = fmaf(w.w, vc.w, zp1);
      zt1 = fmaf(w.x, vd.x, zt1); zt1 = fmaf(w.y, vd.y, zt1);
      zt1 = fmaf(w.z, vd.z, zt1); zt1 = fmaf(w.w, vd.w, zt1);
    }
    loss += fabsf(fast_tanh(zp0) - fast_tanh(zt0));
    loss += fabsf(fast_tanh(zp1) - fast_tanh(zt1));
    __syncthreads();
  }

  // block reduction -> one double atomic per workgroup
  #pragma unroll
  for (int off = 32; off > 0; off >>= 1) loss += __shfl_down(loss, off);
  if ((tid & 63) == 0) red[tid >> 6] = loss;
  __syncthreads();
  if (tid == 0) atomicAdd(wsum, (double)(red[0] + red[1] + red[2] + red[3]));
}

__global__ void finalize(const double* __restrict__ wsum, float* __restrict__ out) {
  out[0] = (float)(wsum[0] / NVALID);
}

extern "C" void kernel_launch(void* const* d_in, const int* in_sizes, int n_in,
                              void* d_out, int out_size, void* d_ws, size_t ws_size,
                              hipStream_t stream) {
  const float* pred = (const float*)d_in[0];
  const float* tgt  = (const float*)d_in[1];
  const float* W    = (const float*)d_in[5];
  float* out = (float*)d_out;

  double* base = (double*)d_ws;
  double* wsum = base;                      // [1] (pad to 8)
  double* ca1  = base + 8;                  // [64]
  double* ca2  = base + 72;                 // [64]
  double* cb0  = base + 136;                // [64]
  double* fbuf = base + 200;                // [P][1024][2]
  double* ibuf = fbuf + (size_t)PBLK * 1024 * 2;  // [P+1][1024][2]

  canon_coeffs<<<1, 64, 0, stream>>>(d_in[2], d_in[3], d_in[4], ca1, ca2, cb0, wsum);
  pass1<<<dim3(PBLK, 16), 64, 0, stream>>>(pred, tgt, ca1, ca2, cb0, fbuf);
  pass2<<<dim3(4), 256, 0, stream>>>(ca1, ca2, fbuf, ibuf);
  pass3<<<dim3(NKV, BATCH), 256, 0, stream>>>(pred, tgt, ca1, ca2, cb0, W, ibuf, wsum);
  finalize<<<1, 1, 0, stream>>>(wsum, out);
}